// Round 10
// baseline (219.878 us; speedup 1.0000x reference)
//
#include <hip/hip_runtime.h>
#include <stdint.h>

typedef unsigned short u16;
typedef __attribute__((ext_vector_type(8))) short bf16x8;
typedef __attribute__((ext_vector_type(4))) short bf16x4;
typedef __attribute__((ext_vector_type(4))) float f32x4;
typedef __attribute__((ext_vector_type(4))) unsigned short u16x4;

__device__ __forceinline__ u16 f2b(float f) {  // fp32 -> bf16 bits, RNE
  union { float f; unsigned u; } v; v.f = f;
  unsigned r = v.u + 0x7FFFu + ((v.u >> 16) & 1u);
  return (u16)(r >> 16);
}

__device__ __forceinline__ float fexp2(float x) {
#if __has_builtin(__builtin_amdgcn_exp2f)
  return __builtin_amdgcn_exp2f(x);
#else
  return exp2f(x);
#endif
}

// ---------------- weights fp32 -> bf16 (proj_w then out_w, one launch) ----
__global__ __launch_bounds__(256) void cvt_kernel(const float* __restrict__ wq_f,
                                                  const float* __restrict__ wo_f,
                                                  u16* __restrict__ wq,
                                                  u16* __restrict__ wo) {
  int i = blockIdx.x * 256 + threadIdx.x;   // 0 .. 262143
  const float* src; u16* dst; int j;
  if (i < 196608) { src = wq_f; dst = wq; j = i; }
  else            { src = wo_f; dst = wo; j = i - 196608; }
  const float4 f = ((const float4*)src)[j];
  u16x4 r; r[0] = f2b(f.x); r[1] = f2b(f.y); r[2] = f2b(f.z); r[3] = f2b(f.w);
  *(u16x4*)(dst + (size_t)j * 4) = r;
}

// ---------------- GroupNorm + transpose to h[B,S,C] bf16 ----------------
__global__ __launch_bounds__(256) void gn_kernel(const float* __restrict__ x,
                                                 const float* __restrict__ gw,
                                                 const float* __restrict__ gb,
                                                 u16* __restrict__ h) {
  const int b = blockIdx.x >> 5, g = blockIdx.x & 31;
  const float* xg = x + ((size_t)(b * 512 + g * 16)) * 1024;
  const int tid = threadIdx.x;
  float vals[64];
  float s = 0.f, ss = 0.f;
#pragma unroll
  for (int i = 0; i < 64; i++) {
    float vv = xg[i * 256 + tid];
    vals[i] = vv; s += vv; ss += vv * vv;
  }
#pragma unroll
  for (int off = 32; off; off >>= 1) { s += __shfl_down(s, off); ss += __shfl_down(ss, off); }
  __shared__ float red[8];
  const int wid = tid >> 6, lane = tid & 63;
  if (lane == 0) { red[wid] = s; red[4 + wid] = ss; }
  __syncthreads();
  if (tid == 0) {
    float S = red[0] + red[1] + red[2] + red[3];
    float SS = red[4] + red[5] + red[6] + red[7];
    float mean = S * (1.f / 16384.f);
    float var = SS * (1.f / 16384.f) - mean * mean;
    red[0] = mean; red[1] = rsqrtf(var + 1e-5f);
  }
  __syncthreads();
  const float mean = red[0], rs = red[1];
  float sc[16], bi[16];
#pragma unroll
  for (int c = 0; c < 16; c++) { sc[c] = gw[g * 16 + c] * rs; bi[c] = gb[g * 16 + c]; }
#pragma unroll
  for (int h4 = 0; h4 < 4; h4++) {
    const int sp = h4 * 256 + tid;
    u16 row[16];
#pragma unroll
    for (int c = 0; c < 16; c++)
      row[c] = f2b((vals[c * 4 + h4] - mean) * sc[c] + bi[c]);
    u16* dst = h + ((size_t)(b * 1024 + sp)) * 512 + g * 16;
    *(bf16x8*)dst = *(bf16x8*)&row[0];
    *(bf16x8*)(dst + 8) = *(bf16x8*)&row[8];
  }
}

// LDS tile geometry for the two GEMMs: 128 rows x 32 cols bf16, row stride 36
// (pad +4): ds_read_b128 beat groups hit dwords {0,18,4,22,8,26,12,30}*... ->
// all 32 banks exactly once (conflict-free); ds_write_b128 is 2-way (free).
#define TSTRIDE 36

// ---------------- QKV GEMM v2: dbuf LDS, 1 barrier/kt, padded stride ------
// q,k stored [B,H,S,D]; v stored TRANSPOSED [B,H,D,S].
// q additionally carries log2(e) so attention can use exp2 directly.
__global__ __launch_bounds__(256) void qkv_gemm(const u16* __restrict__ h,
                                                const u16* __restrict__ w,
                                                const float* __restrict__ bias,
                                                u16* __restrict__ q,
                                                u16* __restrict__ k,
                                                u16* __restrict__ v) {
  __shared__ u16 As[2][128 * TSTRIDE];
  __shared__ u16 Bs[2][128 * TSTRIDE];
  const int b = blockIdx.z;
  const int bm = blockIdx.x;
  const int bn = blockIdx.y;
  const int tid = threadIdx.x, lane = tid & 63, wid = tid >> 6;
  const int wm = wid & 1, wn = wid >> 1;
  const u16* gA = h + ((size_t)b * 1024 + bm * 128) * 512;
  const u16* gB = w + (size_t)bn * 128 * 512;

  const f32x4 fz = {0.f, 0.f, 0.f, 0.f};
  f32x4 acc[4][4];
#pragma unroll
  for (int i = 0; i < 4; i++)
#pragma unroll
    for (int j = 0; j < 4; j++) acc[i][j] = fz;

  // staging mapping: j=0,1 -> row (wid*2+j)*16 + lane>>2, col (lane&3)*8
  int srow[2], soff[2];
#pragma unroll
  for (int j = 0; j < 2; j++) {
    srow[j] = (wid * 2 + j) * 16 + (lane >> 2);
    soff[j] = srow[j] * TSTRIDE + (lane & 3) * 8;
  }
  const int ch8 = (lane & 3) * 8;
  const int c15 = lane & 15, quad = lane >> 4;

  bf16x8 ar[2], br[2];
#pragma unroll
  for (int j = 0; j < 2; j++) {       // tile 0 into regs
    ar[j] = *(const bf16x8*)(gA + (size_t)srow[j] * 512 + ch8);
    br[j] = *(const bf16x8*)(gB + (size_t)srow[j] * 512 + ch8);
  }
#pragma unroll
  for (int j = 0; j < 2; j++) {       // tile 0 -> buf0
    *(bf16x8*)&As[0][soff[j]] = ar[j];
    *(bf16x8*)&Bs[0][soff[j]] = br[j];
  }
#pragma unroll
  for (int j = 0; j < 2; j++) {       // tile 1 into regs
    ar[j] = *(const bf16x8*)(gA + (size_t)srow[j] * 512 + 32 + ch8);
    br[j] = *(const bf16x8*)(gB + (size_t)srow[j] * 512 + 32 + ch8);
  }

  for (int kt = 0; kt < 16; ++kt) {
    __syncthreads();   // publish buf[kt&1]; retire readers of buf[(kt&1)^1]
    const int cur = kt & 1, alt = cur ^ 1;
    if (kt < 15) {
#pragma unroll
      for (int j = 0; j < 2; j++) {
        *(bf16x8*)&As[alt][soff[j]] = ar[j];
        *(bf16x8*)&Bs[alt][soff[j]] = br[j];
      }
      const int pk2 = (kt + 2) & 15;
#pragma unroll
      for (int j = 0; j < 2; j++) {
        ar[j] = *(const bf16x8*)(gA + (size_t)srow[j] * 512 + pk2 * 32 + ch8);
        br[j] = *(const bf16x8*)(gB + (size_t)srow[j] * 512 + pk2 * 32 + ch8);
      }
    }
    bf16x8 af[4], bf[4];
#pragma unroll
    for (int mi = 0; mi < 4; mi++)
      af[mi] = *(const bf16x8*)&As[cur][(wm * 64 + mi * 16 + c15) * TSTRIDE + quad * 8];
#pragma unroll
    for (int ni = 0; ni < 4; ni++)
      bf[ni] = *(const bf16x8*)&Bs[cur][(wn * 64 + ni * 16 + c15) * TSTRIDE + quad * 8];
#pragma unroll
    for (int mi = 0; mi < 4; mi++)
#pragma unroll
      for (int ni = 0; ni < 4; ni++)
        acc[mi][ni] = __builtin_amdgcn_mfma_f32_16x16x32_bf16(af[mi], bf[ni], acc[mi][ni], 0, 0, 0);
  }

  const float qscale = 0.51006972f;            // 2^-1.5 * log2(e)
  const float kscale = 0.35355339059327373f;   // 2^-1.5
  const int quad4 = quad << 2;
#pragma unroll
  for (int mi = 0; mi < 4; mi++) {
    const int m = bm * 128 + wm * 64 + mi * 16 + quad4;
#pragma unroll
    for (int ni = 0; ni < 4; ni++) {
      const int n = bn * 128 + wn * 64 + ni * 16 + c15;
      const int head = n / 192;
      const int rr = n - head * 192;
      const float bi = bias[n];
      const int d = rr & 63;
      if (rr < 128) {
        u16* dst = (rr < 64) ? q : k;
        const float sc = (rr < 64) ? qscale : kscale;
        dst += ((size_t)(b * 8 + head) * 1024 + m) * 64 + d;
#pragma unroll
        for (int r = 0; r < 4; r++)
          dst[(size_t)r * 64] = f2b((acc[mi][ni][r] + bi) * sc);
      } else {
        u16x4 pk;
#pragma unroll
        for (int r = 0; r < 4; r++) pk[r] = f2b(acc[mi][ni][r] + bi);
        *(u16x4*)(v + ((size_t)(b * 8 + head) * 64 + d) * 1024 + m) = pk;
      }
    }
  }
}

// ---------------- flash attention v9 (unchanged from round 9) -------------
__global__ __launch_bounds__(256) void attn_kernel(const u16* __restrict__ q,
                                                   const u16* __restrict__ k,
                                                   const u16* __restrict__ vT,
                                                   u16* __restrict__ o) {
  __shared__ u16 Ks[2][64 * 64];
  __shared__ u16 Vs[2][64 * 64];
  const int bh = blockIdx.x;
  const int qb = blockIdx.y;      // 0..7
  const int tid = threadIdx.x, lane = tid & 63, wid = tid >> 6;
  const u16* Q = q + (size_t)bh * 1024 * 64;
  const u16* K = k + (size_t)bh * 1024 * 64;
  const u16* V = vT + (size_t)bh * 64 * 1024;
  const int qrow0 = qb * 128 + wid * 32;
  const int c15 = lane & 15, quad = lane >> 4;
  const int sw = c15 & 7;
  const int srow = tid >> 2;
  const int t4 = tid & 3;
  const int s7 = srow & 7;
  const int kld0 = srow * 64 + (((t4 * 2) ^ s7) * 8);
  const int kld1 = srow * 64 + (((t4 * 2 + 1) ^ s7) * 8);
  int vld[4];
#pragma unroll
  for (int qq = 0; qq < 4; qq++)
    vld[qq] = srow * 64 + ((((t4 >> 1) * 4 + qq) ^ s7) * 8) + (t4 & 1) * 4;

  bf16x8 qf[2][2];
#pragma unroll
  for (int kk = 0; kk < 2; kk++)
#pragma unroll
    for (int ni = 0; ni < 2; ni++)
      qf[kk][ni] = *(const bf16x8*)(Q + (size_t)(qrow0 + ni * 16 + c15) * 64 + kk * 32 + quad * 8);

  const f32x4 fz = {0.f, 0.f, 0.f, 0.f};
  const float Mshift = 14.4269504089f;     // 10 * log2(e)
  const f32x4 fm = {-Mshift, -Mshift, -Mshift, -Mshift};
  f32x4 oaccT[4][2];
#pragma unroll
  for (int i = 0; i < 4; i++)
#pragma unroll
    for (int j = 0; j < 2; j++) oaccT[i][j] = fz;
  float lsum[2] = {0.f, 0.f};

  bf16x8 kr0, kr1, vr0, vr1;
  {
    const u16* Kn = K + (size_t)srow * 64 + t4 * 16;
    kr0 = *(const bf16x8*)(Kn); kr1 = *(const bf16x8*)(Kn + 8);
    const u16* Vn = V + (size_t)srow * 1024 + t4 * 16;
    vr0 = *(const bf16x8*)(Vn); vr1 = *(const bf16x8*)(Vn + 8);
  }
  {
    u16* Kd = Ks[0]; u16* Vd = Vs[0];
    *(bf16x8*)&Kd[kld0] = kr0; *(bf16x8*)&Kd[kld1] = kr1;
    union { bf16x4 h[2]; bf16x8 v; } a0, a1;
    a0.v = vr0; a1.v = vr1;
    *(bf16x4*)&Vd[vld[0]] = a0.h[0];
    *(bf16x4*)&Vd[vld[1]] = a0.h[1];
    *(bf16x4*)&Vd[vld[2]] = a1.h[0];
    *(bf16x4*)&Vd[vld[3]] = a1.h[1];
  }
  {
    const u16* Kn = K + (size_t)(64 + srow) * 64 + t4 * 16;
    kr0 = *(const bf16x8*)(Kn); kr1 = *(const bf16x8*)(Kn + 8);
    const u16* Vn = V + (size_t)srow * 1024 + 64 + t4 * 16;
    vr0 = *(const bf16x8*)(Vn); vr1 = *(const bf16x8*)(Vn + 8);
  }

  for (int kt = 0; kt < 16; ++kt) {
    __syncthreads();
    const int cur = kt & 1, alt = cur ^ 1;
    if (kt < 15) {
      u16* Kd = Ks[alt]; u16* Vd = Vs[alt];
      *(bf16x8*)&Kd[kld0] = kr0; *(bf16x8*)&Kd[kld1] = kr1;
      union { bf16x4 h[2]; bf16x8 v; } a0, a1;
      a0.v = vr0; a1.v = vr1;
      *(bf16x4*)&Vd[vld[0]] = a0.h[0];
      *(bf16x4*)&Vd[vld[1]] = a0.h[1];
      *(bf16x4*)&Vd[vld[2]] = a1.h[0];
      *(bf16x4*)&Vd[vld[3]] = a1.h[1];
      const int pk2 = (kt + 2) & 15;
      const u16* Kn = K + ((size_t)pk2 * 64 + srow) * 64 + t4 * 16;
      kr0 = *(const bf16x8*)(Kn); kr1 = *(const bf16x8*)(Kn + 8);
      const u16* Vn = V + (size_t)srow * 1024 + pk2 * 64 + t4 * 16;
      vr0 = *(const bf16x8*)(Vn); vr1 = *(const bf16x8*)(Vn + 8);
    }
    const u16* Kc = Ks[cur];
    const u16* Vc = Vs[cur];

    f32x4 sacc[4][2];
#pragma unroll
    for (int i = 0; i < 4; i++)
#pragma unroll
      for (int j = 0; j < 2; j++) sacc[i][j] = fm;
#pragma unroll
    for (int kk = 0; kk < 2; kk++) {
      bf16x8 af[4];
#pragma unroll
      for (int mi = 0; mi < 4; mi++)
        af[mi] = *(const bf16x8*)&Kc[(mi * 16 + c15) * 64 + (((kk * 4 + quad) ^ sw) * 8)];
#pragma unroll
      for (int mi = 0; mi < 4; mi++)
#pragma unroll
        for (int ni = 0; ni < 2; ni++)
          sacc[mi][ni] = __builtin_amdgcn_mfma_f32_16x16x32_bf16(af[mi], qf[kk][ni], sacc[mi][ni], 0, 0, 0);
    }

    unsigned pkd[4][2][2];
#pragma unroll
    for (int ni = 0; ni < 2; ni++) {
      float ls = 0.f;
#pragma unroll
      for (int mi = 0; mi < 4; mi++) {
        unsigned pu[4];
#pragma unroll
        for (int r = 0; r < 4; r++) {
          const float p = fexp2(sacc[mi][ni][r]);
          ls += p;
          union { float f; unsigned u; } c; c.f = p;
          pu[r] = c.u;
        }
        pkd[mi][ni][0] = __builtin_amdgcn_perm(pu[1], pu[0], 0x07060302u);
        pkd[mi][ni][1] = __builtin_amdgcn_perm(pu[3], pu[2], 0x07060302u);
      }
      lsum[ni] += ls;
    }

#pragma unroll
    for (int mg = 0; mg < 2; mg++) {
      union { unsigned u[4]; bf16x8 v; } bb[2];
#pragma unroll
      for (int ni = 0; ni < 2; ni++) {
        bb[ni].u[0] = pkd[2 * mg][ni][0];     bb[ni].u[1] = pkd[2 * mg][ni][1];
        bb[ni].u[2] = pkd[2 * mg + 1][ni][0]; bb[ni].u[3] = pkd[2 * mg + 1][ni][1];
      }
#pragma unroll
      for (int nd = 0; nd < 4; nd++) {
        const bf16x8 aa = *(const bf16x8*)&Vc[(nd * 16 + c15) * 64 + (((mg * 4 + quad) ^ sw) * 8)];
#pragma unroll
        for (int ni = 0; ni < 2; ni++)
          oaccT[nd][ni] = __builtin_amdgcn_mfma_f32_16x16x32_bf16(aa, bb[ni].v, oaccT[nd][ni], 0, 0, 0);
      }
    }
  }

  float iv[2];
#pragma unroll
  for (int ni = 0; ni < 2; ni++) {
    float l = lsum[ni];
    l += __shfl_xor(l, 16);
    l += __shfl_xor(l, 32);
    iv[ni] = 1.f / l;
  }
  const int b = bh >> 3, hh = bh & 7;
#pragma unroll
  for (int ni = 0; ni < 2; ni++) {
    const int row = qrow0 + ni * 16 + c15;
#pragma unroll
    for (int nd = 0; nd < 4; nd++) {
      u16x4 pk4;
#pragma unroll
      for (int r = 0; r < 4; r++) pk4[r] = f2b(oaccT[nd][ni][r] * iv[ni]);
      *(u16x4*)(o + ((size_t)b * 1024 + row) * 512 + hh * 64 + nd * 16 + quad * 4) = pk4;
    }
  }
}

// ---------------- out proj v2: dbuf LDS, 1 barrier/kt, padded stride ------
// (operands swapped: D[c][s]) + bias + residual
__global__ __launch_bounds__(256) void out_gemm(const u16* __restrict__ wo,
                                                const u16* __restrict__ attn,
                                                const float* __restrict__ ob,
                                                const float* __restrict__ x,
                                                float* __restrict__ out) {
  __shared__ u16 As[2][128 * TSTRIDE];
  __shared__ u16 Bs[2][128 * TSTRIDE];
  const int b = blockIdx.z;
  const int bm = blockIdx.x;
  const int bn = blockIdx.y;
  const int tid = threadIdx.x, lane = tid & 63, wid = tid >> 6;
  const int wm = wid & 1, wn = wid >> 1;
  const u16* gA = wo + (size_t)bm * 128 * 512;
  const u16* gB = attn + ((size_t)b * 1024 + bn * 128) * 512;

  const f32x4 fz = {0.f, 0.f, 0.f, 0.f};
  f32x4 acc[4][4];
#pragma unroll
  for (int i = 0; i < 4; i++)
#pragma unroll
    for (int j = 0; j < 4; j++) acc[i][j] = fz;

  int srow[2], soff[2];
#pragma unroll
  for (int j = 0; j < 2; j++) {
    srow[j] = (wid * 2 + j) * 16 + (lane >> 2);
    soff[j] = srow[j] * TSTRIDE + (lane & 3) * 8;
  }
  const int ch8 = (lane & 3) * 8;
  const int c15 = lane & 15, quad = lane >> 4;

  bf16x8 ar[2], br[2];
#pragma unroll
  for (int j = 0; j < 2; j++) {
    ar[j] = *(const bf16x8*)(gA + (size_t)srow[j] * 512 + ch8);
    br[j] = *(const bf16x8*)(gB + (size_t)srow[j] * 512 + ch8);
  }
#pragma unroll
  for (int j = 0; j < 2; j++) {
    *(bf16x8*)&As[0][soff[j]] = ar[j];
    *(bf16x8*)&Bs[0][soff[j]] = br[j];
  }
#pragma unroll
  for (int j = 0; j < 2; j++) {
    ar[j] = *(const bf16x8*)(gA + (size_t)srow[j] * 512 + 32 + ch8);
    br[j] = *(const bf16x8*)(gB + (size_t)srow[j] * 512 + 32 + ch8);
  }

  for (int kt = 0; kt < 16; ++kt) {
    __syncthreads();
    const int cur = kt & 1, alt = cur ^ 1;
    if (kt < 15) {
#pragma unroll
      for (int j = 0; j < 2; j++) {
        *(bf16x8*)&As[alt][soff[j]] = ar[j];
        *(bf16x8*)&Bs[alt][soff[j]] = br[j];
      }
      const int pk2 = (kt + 2) & 15;
#pragma unroll
      for (int j = 0; j < 2; j++) {
        ar[j] = *(const bf16x8*)(gA + (size_t)srow[j] * 512 + pk2 * 32 + ch8);
        br[j] = *(const bf16x8*)(gB + (size_t)srow[j] * 512 + pk2 * 32 + ch8);
      }
    }
    bf16x8 af[4], bf[4];
#pragma unroll
    for (int mi = 0; mi < 4; mi++)
      af[mi] = *(const bf16x8*)&As[cur][(wm * 64 + mi * 16 + c15) * TSTRIDE + quad * 8];
#pragma unroll
    for (int ni = 0; ni < 4; ni++)
      bf[ni] = *(const bf16x8*)&Bs[cur][(wn * 64 + ni * 16 + c15) * TSTRIDE + quad * 8];
#pragma unroll
    for (int mi = 0; mi < 4; mi++)
#pragma unroll
      for (int ni = 0; ni < 4; ni++)
        acc[mi][ni] = __builtin_amdgcn_mfma_f32_16x16x32_bf16(af[mi], bf[ni], acc[mi][ni], 0, 0, 0);
  }

  const int quad4 = quad << 2;
#pragma unroll
  for (int mi = 0; mi < 4; mi++) {
    const int c = bm * 128 + wm * 64 + mi * 16 + quad4;
#pragma unroll
    for (int ni = 0; ni < 4; ni++) {
      const int s = bn * 128 + wn * 64 + ni * 16 + c15;
#pragma unroll
      for (int r = 0; r < 4; r++) {
        const int cc = c + r;
        const size_t idx = ((size_t)b * 512 + cc) * 1024 + s;
        out[idx] = acc[mi][ni][r] + ob[cc] + x[idx];
      }
    }
  }
}

extern "C" void kernel_launch(void* const* d_in, const int* in_sizes, int n_in,
                              void* d_out, int out_size, void* d_ws, size_t ws_size,
                              hipStream_t stream) {
  const float* x      = (const float*)d_in[0];
  const float* gn_w   = (const float*)d_in[1];
  const float* gn_b   = (const float*)d_in[2];
  const float* proj_w = (const float*)d_in[3];
  const float* proj_b = (const float*)d_in[4];
  const float* out_w  = (const float*)d_in[5];
  const float* out_b  = (const float*)d_in[6];
  float* out = (float*)d_out;

  char* p = (char*)d_ws;
  u16* h    = (u16*)p; p += (size_t)16 * 1024 * 512 * 2;
  u16* q    = (u16*)p; p += (size_t)16 * 8 * 1024 * 64 * 2;
  u16* k    = (u16*)p; p += (size_t)16 * 8 * 1024 * 64 * 2;
  u16* v    = (u16*)p; p += (size_t)16 * 8 * 1024 * 64 * 2;   // [B,H,D,S]
  u16* attn = (u16*)p; p += (size_t)16 * 1024 * 512 * 2;
  u16* wq   = (u16*)p; p += (size_t)1536 * 512 * 2;
  u16* wo   = (u16*)p; p += (size_t)512 * 512 * 2;

  cvt_kernel<<<1024, 256, 0, stream>>>(proj_w, out_w, wq, wo);
  gn_kernel<<<512, 256, 0, stream>>>(x, gn_w, gn_b, h);
  qkv_gemm<<<dim3(8, 12, 16), 256, 0, stream>>>(h, wq, proj_b, q, k, v);
  attn_kernel<<<dim3(128, 8, 1), 256, 0, stream>>>(q, k, v, attn);
  out_gemm<<<dim3(4, 8, 16), 256, 0, stream>>>(wo, attn, out_b, x, out);
}

// Round 11
// 216.641 us; speedup vs baseline: 1.0149x; 1.0149x over previous
//
#include <hip/hip_runtime.h>
#include <stdint.h>

typedef unsigned short u16;
typedef __attribute__((ext_vector_type(8))) short bf16x8;
typedef __attribute__((ext_vector_type(4))) short bf16x4;
typedef __attribute__((ext_vector_type(4))) float f32x4;
typedef __attribute__((ext_vector_type(4))) unsigned short u16x4;

__device__ __forceinline__ u16 f2b(float f) {  // fp32 -> bf16 bits, RNE
  union { float f; unsigned u; } v; v.f = f;
  unsigned r = v.u + 0x7FFFu + ((v.u >> 16) & 1u);
  return (u16)(r >> 16);
}

__device__ __forceinline__ float fexp2(float x) {
#if __has_builtin(__builtin_amdgcn_exp2f)
  return __builtin_amdgcn_exp2f(x);
#else
  return exp2f(x);
#endif
}

// ---------------- weights fp32 -> bf16 (proj_w then out_w, one launch) ----
__global__ __launch_bounds__(256) void cvt_kernel(const float* __restrict__ wq_f,
                                                  const float* __restrict__ wo_f,
                                                  u16* __restrict__ wq,
                                                  u16* __restrict__ wo) {
  int i = blockIdx.x * 256 + threadIdx.x;   // 0 .. 262143
  const float* src; u16* dst; int j;
  if (i < 196608) { src = wq_f; dst = wq; j = i; }
  else            { src = wo_f; dst = wo; j = i - 196608; }
  const float4 f = ((const float4*)src)[j];
  u16x4 r; r[0] = f2b(f.x); r[1] = f2b(f.y); r[2] = f2b(f.z); r[3] = f2b(f.w);
  *(u16x4*)(dst + (size_t)j * 4) = r;
}

// ---------------- GroupNorm + transpose to h[B,S,C] bf16 ----------------
__global__ __launch_bounds__(256) void gn_kernel(const float* __restrict__ x,
                                                 const float* __restrict__ gw,
                                                 const float* __restrict__ gb,
                                                 u16* __restrict__ h) {
  const int b = blockIdx.x >> 5, g = blockIdx.x & 31;
  const float* xg = x + ((size_t)(b * 512 + g * 16)) * 1024;
  const int tid = threadIdx.x;
  float vals[64];
  float s = 0.f, ss = 0.f;
#pragma unroll
  for (int i = 0; i < 64; i++) {
    float vv = xg[i * 256 + tid];
    vals[i] = vv; s += vv; ss += vv * vv;
  }
#pragma unroll
  for (int off = 32; off; off >>= 1) { s += __shfl_down(s, off); ss += __shfl_down(ss, off); }
  __shared__ float red[8];
  const int wid = tid >> 6, lane = tid & 63;
  if (lane == 0) { red[wid] = s; red[4 + wid] = ss; }
  __syncthreads();
  if (tid == 0) {
    float S = red[0] + red[1] + red[2] + red[3];
    float SS = red[4] + red[5] + red[6] + red[7];
    float mean = S * (1.f / 16384.f);
    float var = SS * (1.f / 16384.f) - mean * mean;
    red[0] = mean; red[1] = rsqrtf(var + 1e-5f);
  }
  __syncthreads();
  const float mean = red[0], rs = red[1];
  float sc[16], bi[16];
#pragma unroll
  for (int c = 0; c < 16; c++) { sc[c] = gw[g * 16 + c] * rs; bi[c] = gb[g * 16 + c]; }
#pragma unroll
  for (int h4 = 0; h4 < 4; h4++) {
    const int sp = h4 * 256 + tid;
    u16 row[16];
#pragma unroll
    for (int c = 0; c < 16; c++)
      row[c] = f2b((vals[c * 4 + h4] - mean) * sc[c] + bi[c]);
    u16* dst = h + ((size_t)(b * 1024 + sp)) * 512 + g * 16;
    *(bf16x8*)dst = *(bf16x8*)&row[0];
    *(bf16x8*)(dst + 8) = *(bf16x8*)&row[8];
  }
}

// LDS tile geometry for the two GEMMs: 128 rows x 32 cols bf16, row stride 36
// (pad +4): conflict-free reads, 2-way (free) writes.
#define TSTRIDE 36

// ---------------- QKV GEMM v2: dbuf LDS, 1 barrier/kt, padded stride ------
// q,k stored [B,H,S,D]; v stored TRANSPOSED [B,H,D,S].
// q additionally carries log2(e) so attention can use exp2 directly.
__global__ __launch_bounds__(256) void qkv_gemm(const u16* __restrict__ h,
                                                const u16* __restrict__ w,
                                                const float* __restrict__ bias,
                                                u16* __restrict__ q,
                                                u16* __restrict__ k,
                                                u16* __restrict__ v) {
  __shared__ u16 As[2][128 * TSTRIDE];
  __shared__ u16 Bs[2][128 * TSTRIDE];
  const int b = blockIdx.z;
  const int bm = blockIdx.x;
  const int bn = blockIdx.y;
  const int tid = threadIdx.x, lane = tid & 63, wid = tid >> 6;
  const int wm = wid & 1, wn = wid >> 1;
  const u16* gA = h + ((size_t)b * 1024 + bm * 128) * 512;
  const u16* gB = w + (size_t)bn * 128 * 512;

  const f32x4 fz = {0.f, 0.f, 0.f, 0.f};
  f32x4 acc[4][4];
#pragma unroll
  for (int i = 0; i < 4; i++)
#pragma unroll
    for (int j = 0; j < 4; j++) acc[i][j] = fz;

  int srow[2], soff[2];
#pragma unroll
  for (int j = 0; j < 2; j++) {
    srow[j] = (wid * 2 + j) * 16 + (lane >> 2);
    soff[j] = srow[j] * TSTRIDE + (lane & 3) * 8;
  }
  const int ch8 = (lane & 3) * 8;
  const int c15 = lane & 15, quad = lane >> 4;

  bf16x8 ar[2], br[2];
#pragma unroll
  for (int j = 0; j < 2; j++) {
    ar[j] = *(const bf16x8*)(gA + (size_t)srow[j] * 512 + ch8);
    br[j] = *(const bf16x8*)(gB + (size_t)srow[j] * 512 + ch8);
  }
#pragma unroll
  for (int j = 0; j < 2; j++) {
    *(bf16x8*)&As[0][soff[j]] = ar[j];
    *(bf16x8*)&Bs[0][soff[j]] = br[j];
  }
#pragma unroll
  for (int j = 0; j < 2; j++) {
    ar[j] = *(const bf16x8*)(gA + (size_t)srow[j] * 512 + 32 + ch8);
    br[j] = *(const bf16x8*)(gB + (size_t)srow[j] * 512 + 32 + ch8);
  }

  for (int kt = 0; kt < 16; ++kt) {
    __syncthreads();
    const int cur = kt & 1, alt = cur ^ 1;
    if (kt < 15) {
#pragma unroll
      for (int j = 0; j < 2; j++) {
        *(bf16x8*)&As[alt][soff[j]] = ar[j];
        *(bf16x8*)&Bs[alt][soff[j]] = br[j];
      }
      const int pk2 = (kt + 2) & 15;
#pragma unroll
      for (int j = 0; j < 2; j++) {
        ar[j] = *(const bf16x8*)(gA + (size_t)srow[j] * 512 + pk2 * 32 + ch8);
        br[j] = *(const bf16x8*)(gB + (size_t)srow[j] * 512 + pk2 * 32 + ch8);
      }
    }
    bf16x8 af[4], bf[4];
#pragma unroll
    for (int mi = 0; mi < 4; mi++)
      af[mi] = *(const bf16x8*)&As[cur][(wm * 64 + mi * 16 + c15) * TSTRIDE + quad * 8];
#pragma unroll
    for (int ni = 0; ni < 4; ni++)
      bf[ni] = *(const bf16x8*)&Bs[cur][(wn * 64 + ni * 16 + c15) * TSTRIDE + quad * 8];
#pragma unroll
    for (int mi = 0; mi < 4; mi++)
#pragma unroll
      for (int ni = 0; ni < 4; ni++)
        acc[mi][ni] = __builtin_amdgcn_mfma_f32_16x16x32_bf16(af[mi], bf[ni], acc[mi][ni], 0, 0, 0);
  }

  const float qscale = 0.51006972f;            // 2^-1.5 * log2(e)
  const float kscale = 0.35355339059327373f;   // 2^-1.5
  const int quad4 = quad << 2;
#pragma unroll
  for (int mi = 0; mi < 4; mi++) {
    const int m = bm * 128 + wm * 64 + mi * 16 + quad4;
#pragma unroll
    for (int ni = 0; ni < 4; ni++) {
      const int n = bn * 128 + wn * 64 + ni * 16 + c15;
      const int head = n / 192;
      const int rr = n - head * 192;
      const float bi = bias[n];
      const int d = rr & 63;
      if (rr < 128) {
        u16* dst = (rr < 64) ? q : k;
        const float sc = (rr < 64) ? qscale : kscale;
        dst += ((size_t)(b * 8 + head) * 1024 + m) * 64 + d;
#pragma unroll
        for (int r = 0; r < 4; r++)
          dst[(size_t)r * 64] = f2b((acc[mi][ni][r] + bi) * sc);
      } else {
        u16x4 pk;
#pragma unroll
        for (int r = 0; r < 4; r++) pk[r] = f2b(acc[mi][ni][r] + bi);
        *(u16x4*)(v + ((size_t)(b * 8 + head) * 64 + d) * 1024 + m) = pk;
      }
    }
  }
}

// ---------------- flash attention v10: 64 Q-rows/wave, V-frags cached -----
// grid = (B*H=128, S/256=4), 2 blocks/CU. 4 waves x 64 Q rows; K/V tiles 64.
// Same machinery as v9 (dbuf stride-64 XOR-swizzled LDS, permuted-key V,
// in-register P PV, exp2 fixed-M softmax) but each wave computes 2 ni-passes
// per kt: V-fragments loaded ONCE into vfr[2][4] and reused by both passes.
// LDS bytes per Q-row drop 25%; waves sharing the LDS port halve (16 -> 8).
__global__ __launch_bounds__(256) void attn_kernel(const u16* __restrict__ q,
                                                   const u16* __restrict__ k,
                                                   const u16* __restrict__ vT,
                                                   u16* __restrict__ o) {
  __shared__ u16 Ks[2][64 * 64];
  __shared__ u16 Vs[2][64 * 64];
  const int bh = blockIdx.x;
  const int qb = blockIdx.y;      // 0..3
  const int tid = threadIdx.x, lane = tid & 63, wid = tid >> 6;
  const u16* Q = q + (size_t)bh * 1024 * 64;
  const u16* K = k + (size_t)bh * 1024 * 64;
  const u16* V = vT + (size_t)bh * 64 * 1024;
  const int qrow0 = qb * 256 + wid * 64;
  const int c15 = lane & 15, quad = lane >> 4;
  const int sw = c15 & 7;
  const int srow = tid >> 2;
  const int t4 = tid & 3;
  const int s7 = srow & 7;
  const int kld0 = srow * 64 + (((t4 * 2) ^ s7) * 8);
  const int kld1 = srow * 64 + (((t4 * 2 + 1) ^ s7) * 8);
  int vld[4];
#pragma unroll
  for (int qq = 0; qq < 4; qq++)
    vld[qq] = srow * 64 + ((((t4 >> 1) * 4 + qq) ^ s7) * 8) + (t4 & 1) * 4;

  // Q as B-operand frags: B[n = ni*16+c15][k = kk*32+quad*8], ni 0..3
  bf16x8 qf[2][4];
#pragma unroll
  for (int kk = 0; kk < 2; kk++)
#pragma unroll
    for (int ni = 0; ni < 4; ni++)
      qf[kk][ni] = *(const bf16x8*)(Q + (size_t)(qrow0 + ni * 16 + c15) * 64 + kk * 32 + quad * 8);

  const f32x4 fz = {0.f, 0.f, 0.f, 0.f};
  const float Mshift = 14.4269504089f;     // 10 * log2(e)
  const f32x4 fm = {-Mshift, -Mshift, -Mshift, -Mshift};
  f32x4 oaccT[4][4];               // O^T[d-tile nd][qrow-tile ni]
#pragma unroll
  for (int i = 0; i < 4; i++)
#pragma unroll
    for (int j = 0; j < 4; j++) oaccT[i][j] = fz;
  float lsum[4] = {0.f, 0.f, 0.f, 0.f};

  // prologue: tile 0 -> buf0; prefetch tile 1 into regs
  bf16x8 kr0, kr1, vr0, vr1;
  {
    const u16* Kn = K + (size_t)srow * 64 + t4 * 16;
    kr0 = *(const bf16x8*)(Kn); kr1 = *(const bf16x8*)(Kn + 8);
    const u16* Vn = V + (size_t)srow * 1024 + t4 * 16;
    vr0 = *(const bf16x8*)(Vn); vr1 = *(const bf16x8*)(Vn + 8);
  }
  {
    u16* Kd = Ks[0]; u16* Vd = Vs[0];
    *(bf16x8*)&Kd[kld0] = kr0; *(bf16x8*)&Kd[kld1] = kr1;
    union { bf16x4 h[2]; bf16x8 v; } a0, a1;
    a0.v = vr0; a1.v = vr1;
    *(bf16x4*)&Vd[vld[0]] = a0.h[0];
    *(bf16x4*)&Vd[vld[1]] = a0.h[1];
    *(bf16x4*)&Vd[vld[2]] = a1.h[0];
    *(bf16x4*)&Vd[vld[3]] = a1.h[1];
  }
  {
    const u16* Kn = K + (size_t)(64 + srow) * 64 + t4 * 16;
    kr0 = *(const bf16x8*)(Kn); kr1 = *(const bf16x8*)(Kn + 8);
    const u16* Vn = V + (size_t)srow * 1024 + 64 + t4 * 16;
    vr0 = *(const bf16x8*)(Vn); vr1 = *(const bf16x8*)(Vn + 8);
  }

  for (int kt = 0; kt < 16; ++kt) {
    __syncthreads();   // publish buf[kt&1]; retire readers of buf[(kt&1)^1]
    const int cur = kt & 1, alt = cur ^ 1;
    if (kt < 15) {
      u16* Kd = Ks[alt]; u16* Vd = Vs[alt];
      *(bf16x8*)&Kd[kld0] = kr0; *(bf16x8*)&Kd[kld1] = kr1;
      union { bf16x4 h[2]; bf16x8 v; } a0, a1;
      a0.v = vr0; a1.v = vr1;
      *(bf16x4*)&Vd[vld[0]] = a0.h[0];
      *(bf16x4*)&Vd[vld[1]] = a0.h[1];
      *(bf16x4*)&Vd[vld[2]] = a1.h[0];
      *(bf16x4*)&Vd[vld[3]] = a1.h[1];
      const int pk2 = (kt + 2) & 15;
      const u16* Kn = K + ((size_t)pk2 * 64 + srow) * 64 + t4 * 16;
      kr0 = *(const bf16x8*)(Kn); kr1 = *(const bf16x8*)(Kn + 8);
      const u16* Vn = V + (size_t)srow * 1024 + pk2 * 64 + t4 * 16;
      vr0 = *(const bf16x8*)(Vn); vr1 = *(const bf16x8*)(Vn + 8);
    }
    const u16* Kc = Ks[cur];
    const u16* Vc = Vs[cur];

    // V-fragments once per kt, reused by both ni-passes
    bf16x8 vfr[2][4];
#pragma unroll
    for (int mg = 0; mg < 2; mg++)
#pragma unroll
      for (int nd = 0; nd < 4; nd++)
        vfr[mg][nd] = *(const bf16x8*)&Vc[(nd * 16 + c15) * 64 + (((mg * 4 + quad) ^ sw) * 8)];

#pragma unroll
    for (int p = 0; p < 2; p++) {    // ni-pass: ni = 2p + nj (nj = 0,1)
      f32x4 sacc[4][2];
#pragma unroll
      for (int i = 0; i < 4; i++)
#pragma unroll
        for (int j = 0; j < 2; j++) sacc[i][j] = fm;
#pragma unroll
      for (int kk = 0; kk < 2; kk++) {
        bf16x8 af[4];
#pragma unroll
        for (int mi = 0; mi < 4; mi++)
          af[mi] = *(const bf16x8*)&Kc[(mi * 16 + c15) * 64 + (((kk * 4 + quad) ^ sw) * 8)];
#pragma unroll
        for (int mi = 0; mi < 4; mi++)
#pragma unroll
          for (int nj = 0; nj < 2; nj++)
            sacc[mi][nj] = __builtin_amdgcn_mfma_f32_16x16x32_bf16(af[mi], qf[kk][2 * p + nj], sacc[mi][nj], 0, 0, 0);
      }

      unsigned pkd[4][2][2];
#pragma unroll
      for (int nj = 0; nj < 2; nj++) {
        float ls = 0.f;
#pragma unroll
        for (int mi = 0; mi < 4; mi++) {
          unsigned pu[4];
#pragma unroll
          for (int r = 0; r < 4; r++) {
            const float pp = fexp2(sacc[mi][nj][r]);
            ls += pp;
            union { float f; unsigned u; } c; c.f = pp;
            pu[r] = c.u;
          }
          pkd[mi][nj][0] = __builtin_amdgcn_perm(pu[1], pu[0], 0x07060302u);
          pkd[mi][nj][1] = __builtin_amdgcn_perm(pu[3], pu[2], 0x07060302u);
        }
        lsum[2 * p + nj] += ls;
      }

#pragma unroll
      for (int mg = 0; mg < 2; mg++) {
        union { unsigned u[4]; bf16x8 v; } bb[2];
#pragma unroll
        for (int nj = 0; nj < 2; nj++) {
          bb[nj].u[0] = pkd[2 * mg][nj][0];     bb[nj].u[1] = pkd[2 * mg][nj][1];
          bb[nj].u[2] = pkd[2 * mg + 1][nj][0]; bb[nj].u[3] = pkd[2 * mg + 1][nj][1];
        }
#pragma unroll
        for (int nd = 0; nd < 4; nd++)
#pragma unroll
          for (int nj = 0; nj < 2; nj++)
            oaccT[nd][2 * p + nj] = __builtin_amdgcn_mfma_f32_16x16x32_bf16(vfr[mg][nd], bb[nj].v, oaccT[nd][2 * p + nj], 0, 0, 0);
      }
    }
  }

  // final l reduction; lane owns its qrows' O^T columns (n=c15)
  float iv[4];
#pragma unroll
  for (int ni = 0; ni < 4; ni++) {
    float l = lsum[ni];
    l += __shfl_xor(l, 16);
    l += __shfl_xor(l, 32);
    iv[ni] = 1.f / l;
  }
  const int b = bh >> 3, hh = bh & 7;
#pragma unroll
  for (int ni = 0; ni < 4; ni++) {
    const int row = qrow0 + ni * 16 + c15;
#pragma unroll
    for (int nd = 0; nd < 4; nd++) {
      u16x4 pk4;
#pragma unroll
      for (int r = 0; r < 4; r++) pk4[r] = f2b(oaccT[nd][ni][r] * iv[ni]);
      *(u16x4*)(o + ((size_t)b * 1024 + row) * 512 + hh * 64 + nd * 16 + quad * 4) = pk4;
    }
  }
}

// ---------------- out proj v2: dbuf LDS, 1 barrier/kt, padded stride ------
__global__ __launch_bounds__(256) void out_gemm(const u16* __restrict__ wo,
                                                const u16* __restrict__ attn,
                                                const float* __restrict__ ob,
                                                const float* __restrict__ x,
                                                float* __restrict__ out) {
  __shared__ u16 As[2][128 * TSTRIDE];
  __shared__ u16 Bs[2][128 * TSTRIDE];
  const int b = blockIdx.z;
  const int bm = blockIdx.x;
  const int bn = blockIdx.y;
  const int tid = threadIdx.x, lane = tid & 63, wid = tid >> 6;
  const int wm = wid & 1, wn = wid >> 1;
  const u16* gA = wo + (size_t)bm * 128 * 512;
  const u16* gB = attn + ((size_t)b * 1024 + bn * 128) * 512;

  const f32x4 fz = {0.f, 0.f, 0.f, 0.f};
  f32x4 acc[4][4];
#pragma unroll
  for (int i = 0; i < 4; i++)
#pragma unroll
    for (int j = 0; j < 4; j++) acc[i][j] = fz;

  int srow[2], soff[2];
#pragma unroll
  for (int j = 0; j < 2; j++) {
    srow[j] = (wid * 2 + j) * 16 + (lane >> 2);
    soff[j] = srow[j] * TSTRIDE + (lane & 3) * 8;
  }
  const int ch8 = (lane & 3) * 8;
  const int c15 = lane & 15, quad = lane >> 4;

  bf16x8 ar[2], br[2];
#pragma unroll
  for (int j = 0; j < 2; j++) {
    ar[j] = *(const bf16x8*)(gA + (size_t)srow[j] * 512 + ch8);
    br[j] = *(const bf16x8*)(gB + (size_t)srow[j] * 512 + ch8);
  }
#pragma unroll
  for (int j = 0; j < 2; j++) {
    *(bf16x8*)&As[0][soff[j]] = ar[j];
    *(bf16x8*)&Bs[0][soff[j]] = br[j];
  }
#pragma unroll
  for (int j = 0; j < 2; j++) {
    ar[j] = *(const bf16x8*)(gA + (size_t)srow[j] * 512 + 32 + ch8);
    br[j] = *(const bf16x8*)(gB + (size_t)srow[j] * 512 + 32 + ch8);
  }

  for (int kt = 0; kt < 16; ++kt) {
    __syncthreads();
    const int cur = kt & 1, alt = cur ^ 1;
    if (kt < 15) {
#pragma unroll
      for (int j = 0; j < 2; j++) {
        *(bf16x8*)&As[alt][soff[j]] = ar[j];
        *(bf16x8*)&Bs[alt][soff[j]] = br[j];
      }
      const int pk2 = (kt + 2) & 15;
#pragma unroll
      for (int j = 0; j < 2; j++) {
        ar[j] = *(const bf16x8*)(gA + (size_t)srow[j] * 512 + pk2 * 32 + ch8);
        br[j] = *(const bf16x8*)(gB + (size_t)srow[j] * 512 + pk2 * 32 + ch8);
      }
    }
    bf16x8 af[4], bf[4];
#pragma unroll
    for (int mi = 0; mi < 4; mi++)
      af[mi] = *(const bf16x8*)&As[cur][(wm * 64 + mi * 16 + c15) * TSTRIDE + quad * 8];
#pragma unroll
    for (int ni = 0; ni < 4; ni++)
      bf[ni] = *(const bf16x8*)&Bs[cur][(wn * 64 + ni * 16 + c15) * TSTRIDE + quad * 8];
#pragma unroll
    for (int mi = 0; mi < 4; mi++)
#pragma unroll
      for (int ni = 0; ni < 4; ni++)
        acc[mi][ni] = __builtin_amdgcn_mfma_f32_16x16x32_bf16(af[mi], bf[ni], acc[mi][ni], 0, 0, 0);
  }

  const int quad4 = quad << 2;
#pragma unroll
  for (int mi = 0; mi < 4; mi++) {
    const int c = bm * 128 + wm * 64 + mi * 16 + quad4;
#pragma unroll
    for (int ni = 0; ni < 4; ni++) {
      const int s = bn * 128 + wn * 64 + ni * 16 + c15;
#pragma unroll
      for (int r = 0; r < 4; r++) {
        const int cc = c + r;
        const size_t idx = ((size_t)b * 512 + cc) * 1024 + s;
        out[idx] = acc[mi][ni][r] + ob[cc] + x[idx];
      }
    }
  }
}

extern "C" void kernel_launch(void* const* d_in, const int* in_sizes, int n_in,
                              void* d_out, int out_size, void* d_ws, size_t ws_size,
                              hipStream_t stream) {
  const float* x      = (const float*)d_in[0];
  const float* gn_w   = (const float*)d_in[1];
  const float* gn_b   = (const float*)d_in[2];
  const float* proj_w = (const float*)d_in[3];
  const float* proj_b = (const float*)d_in[4];
  const float* out_w  = (const float*)d_in[5];
  const float* out_b  = (const float*)d_in[6];
  float* out = (float*)d_out;

  char* p = (char*)d_ws;
  u16* h    = (u16*)p; p += (size_t)16 * 1024 * 512 * 2;
  u16* q    = (u16*)p; p += (size_t)16 * 8 * 1024 * 64 * 2;
  u16* k    = (u16*)p; p += (size_t)16 * 8 * 1024 * 64 * 2;
  u16* v    = (u16*)p; p += (size_t)16 * 8 * 1024 * 64 * 2;   // [B,H,D,S]
  u16* attn = (u16*)p; p += (size_t)16 * 1024 * 512 * 2;
  u16* wq   = (u16*)p; p += (size_t)1536 * 512 * 2;
  u16* wo   = (u16*)p; p += (size_t)512 * 512 * 2;

  cvt_kernel<<<1024, 256, 0, stream>>>(proj_w, out_w, wq, wo);
  gn_kernel<<<512, 256, 0, stream>>>(x, gn_w, gn_b, h);
  qkv_gemm<<<dim3(8, 12, 16), 256, 0, stream>>>(h, wq, proj_b, q, k, v);
  attn_kernel<<<dim3(128, 4, 1), 256, 0, stream>>>(q, k, v, attn);
  out_gemm<<<dim3(4, 8, 16), 256, 0, stream>>>(wo, attn, out_b, x, out);
}